// Round 2
// baseline (213.732 us; speedup 1.0000x reference)
//
#include <hip/hip_runtime.h>
#include <math.h>

#define SEQ   2048
#define DH    64
#define NBH   24
// scale * log2(e): softmax in exp2 domain
#define QSCALE 0.18033688011112042f

typedef __attribute__((ext_vector_type(8))) short short8;
typedef __attribute__((ext_vector_type(4))) short short4v;
typedef __attribute__((ext_vector_type(4))) float f32x4;

#define MFMA32(a, b, c) __builtin_amdgcn_mfma_f32_16x16x32_bf16((a), (b), (c), 0, 0, 0)
// gfx950 v_mfma_f32_16x16x16_bf16 (short4 operands) = the _1k builtin name.
// Direct use (no __has_builtin): feature-gated builtins still parse in the
// HIP host pass (R0 compiled mfma_16x16x32_bf16 unguarded), but
// __has_builtin is FALSE on host -> guarded dispatch breaks host compile (R1).
#define MFMA16(a, b, c) __builtin_amdgcn_mfma_f32_16x16x16bf16_1k((a), (b), (c), 0, 0, 0)

// hardware RNE f32x2 -> packed bf16x2 (m214v22 recipe; no builtin on gfx950)
__device__ __forceinline__ int cvtpk(float lo, float hi) {
    int r;
    asm("v_cvt_pk_bf16_f32 %0, %1, %2" : "=v"(r) : "v"(lo), "v"(hi));
    return r;
}

// ---- fused pre-pass: Q(+scale),K fp32->bf16 row-major; V -> V^T bf16 with
// k-permuted layout: within each 32-seq block, element (m = 16-block parity,
// qq = quad-of-16-block, r) stored at qq*8 + m*4 + r. A single 16B lane-load
// in attn then yields the two 16x16x16 A-frags of a 32-wide k-chunk directly.
__global__ __launch_bounds__(256)
void cvt_all(const float* __restrict__ q, const float* __restrict__ k,
             const float* __restrict__ v,
             short* __restrict__ qb, short* __restrict__ kb,
             short* __restrict__ vt)
{
    __shared__ float tile[64][65];
    const int t  = threadIdx.x;
    const int bh = blockIdx.x;
    const int s0 = blockIdx.y * 64;
    const size_t base = ((size_t)bh * SEQ + s0) * DH;

    #pragma unroll
    for (int i = 0; i < 4; ++i) {
        const int idx = i * 256 + t;
        float4 a = ((const float4*)(q + base))[idx];
        ((int2*)(qb + base))[idx] = make_int2(
            cvtpk(a.x * QSCALE, a.y * QSCALE),
            cvtpk(a.z * QSCALE, a.w * QSCALE));
        float4 b = ((const float4*)(k + base))[idx];
        ((int2*)(kb + base))[idx] = make_int2(cvtpk(b.x, b.y), cvtpk(b.z, b.w));
    }

    {
        const int sl = t >> 2, cg = (t & 3) * 16;
        const float* src = v + base + (size_t)sl * DH + cg;
        #pragma unroll
        for (int i = 0; i < 4; ++i)
            *(float4*)(&tile[sl][cg + 4 * i]) = ((const float4*)src)[i];
    }
    __syncthreads();
    {
        const int dl = t >> 2, sg = (t & 3) * 16;
        float f[16];
        #pragma unroll
        for (int j = 0; j < 16; ++j) f[j] = tile[sg + j][dl];
        short* dst = vt + (size_t)bh * DH * SEQ + (size_t)dl * SEQ
                   + ((s0 + sg) & ~31);
        const int m4 = (sg & 16) ? 4 : 0;    // 16-block parity within 32-block
        #pragma unroll
        for (int qq = 0; qq < 4; ++qq) {
            int2 pc = make_int2(cvtpk(f[4 * qq],     f[4 * qq + 1]),
                                cvtpk(f[4 * qq + 2], f[4 * qq + 3]));
            *(int2*)(dst + qq * 8 + m4) = pc;
        }
    }
}

// ---- main: 4-way split-K flash. Block = 4 waves on ONE 32-row q-tile, each
// wave owns a 512-col K quarter (8 iters of 64). PV uses 16x16x16 MFMAs whose
// B-frag layout (k=quad*4+i, col=l16) IS the QK^T D-layout (row=quad*4+r,
// col=l16) -> P frags are lane-local, no cross-lane shuffles at all.
// Softmax: hw v_cvt_pk_bf16_f32 pack, defer-max (THR=8) skips rescale+reduce
// on the common path, l kept as per-lane partials until the epilogue.
// launch_bounds(256,4): cap 128 VGPR; actual ~84-110 -> 4-6 blocks/CU
// = 16-24 waves/CU vs R6's grid-limited 12.
__global__ __launch_bounds__(256, 4)
void attn_fwd(const short* __restrict__ qb, const short* __restrict__ kb,
              const short* __restrict__ vt, float* __restrict__ og)
{
    __shared__ float lds_o[3][2][64][16];
    __shared__ float lds_m[3][2][16];
    __shared__ float lds_l[3][2][16];

    const int lane = threadIdx.x & 63;
    const int wave = threadIdx.x >> 6;     // k-quarter 0..3
    const int quad = lane >> 4;
    const int l16  = lane & 15;

    // bijective XCD swizzle (1536 = 8 XCD x 192): 3 bh per XCD -> K/V L2-resident
    const int swz = (blockIdx.x & 7) * 192 + (blockIdx.x >> 3);
    const int bh  = swz >> 6;
    const int q0  = (swz & 63) * 32;

    const short* kbase = kb + (size_t)bh * SEQ * DH;
    const short* vbase = vt + (size_t)bh * DH * SEQ;

    short8 bq[2][2];
    #pragma unroll
    for (int qs = 0; qs < 2; ++qs) {
        const short* qrow = qb + ((size_t)(bh * SEQ + q0 + qs * 16 + l16)) * DH + quad * 8;
        bq[qs][0] = *(const short8*)(qrow);
        bq[qs][1] = *(const short8*)(qrow + 32);
    }

    f32x4 o[2][4];
    float m_i[2], l_i[2];
    #pragma unroll
    for (int qs = 0; qs < 2; ++qs) {
        m_i[qs] = -INFINITY; l_i[qs] = 0.f;
        #pragma unroll
        for (int dt = 0; dt < 4; ++dt) o[qs][dt] = (f32x4){0.f, 0.f, 0.f, 0.f};
    }

    const size_t klane = (size_t)l16 * DH + quad * 8;

    int k0 = wave * (SEQ / 4);
    short8 ka[8];
    #pragma unroll
    for (int mt = 0; mt < 4; ++mt) {
        const short* krow = kbase + (size_t)(k0 + mt * 16) * DH + klane;
        ka[2 * mt]     = *(const short8*)(krow);
        ka[2 * mt + 1] = *(const short8*)(krow + 32);
    }

    #pragma unroll 1
    for (int iter = 0; iter < 8; ++iter, k0 += 64) {
        // ---- S^T = K @ Q^T (16x16x32, K=64 per c-tile)
        f32x4 c[2][4];
        #pragma unroll
        for (int mt = 0; mt < 4; ++mt)
            #pragma unroll
            for (int qs = 0; qs < 2; ++qs) {
                f32x4 z = (f32x4){0.f, 0.f, 0.f, 0.f};
                z = MFMA32(ka[2 * mt],     bq[qs][0], z);
                z = MFMA32(ka[2 * mt + 1], bq[qs][1], z);
                c[qs][mt] = z;
            }

        // ---- prefetch next chunk's K frags (in flight through softmax+PV)
        if (iter < 7) {
            const int k0n = k0 + 64;
            #pragma unroll
            for (int mt = 0; mt < 4; ++mt) {
                const short* krow = kbase + (size_t)(k0n + mt * 16) * DH + klane;
                ka[2 * mt]     = *(const short8*)(krow);
                ka[2 * mt + 1] = *(const short8*)(krow + 32);
            }
        }

        // ---- online softmax; P frags stay lane-local (16x16x16 B-layout)
        short4v pb[2][4];
        #pragma unroll
        for (int qs = 0; qs < 2; ++qs) {
            float tm[4];
            #pragma unroll
            for (int e = 0; e < 4; ++e)
                tm[e] = fmaxf(fmaxf(c[qs][0][e], c[qs][1][e]),
                              fmaxf(c[qs][2][e], c[qs][3][e]));
            const float lmax = fmaxf(fmaxf(tm[0], tm[1]), fmaxf(tm[2], tm[3]));
            // defer-max: only rescale when some row grew past m+8 (rare)
            if (!__all(lmax <= m_i[qs] + 8.f)) {
                float vmax = fmaxf(lmax, __shfl_xor(lmax, 16, 64));
                vmax = fmaxf(vmax, __shfl_xor(vmax, 32, 64));
                vmax = fmaxf(vmax, m_i[qs]);
                const float alpha = __builtin_amdgcn_exp2f(m_i[qs] - vmax);
                m_i[qs] = vmax;
                l_i[qs] *= alpha;
                #pragma unroll
                for (int dt = 0; dt < 4; ++dt)
                    #pragma unroll
                    for (int r = 0; r < 4; ++r) o[qs][dt][r] *= alpha;
            }
            const float m = m_i[qs];
            float rs = 0.f;
            #pragma unroll
            for (int mt = 0; mt < 4; ++mt) {
                float p[4];
                #pragma unroll
                for (int r = 0; r < 4; ++r) {
                    p[r] = __builtin_amdgcn_exp2f(c[qs][mt][r] - m);
                    rs += p[r];
                }
                int2 w = make_int2(cvtpk(p[0], p[1]), cvtpk(p[2], p[3]));
                pb[qs][mt] = __builtin_bit_cast(short4v, w);
            }
            l_i[qs] += rs;       // per-lane partial; cross-quad reduce at end
        }

        // ---- PV: shuffle-free. One 16B load = A-frags for both 16-blocks
        // of a 32-chunk (k-permuted vt layout).
        #pragma unroll
        for (int pair = 0; pair < 2; ++pair) {
            short8 av[4];
            #pragma unroll
            for (int dt = 0; dt < 4; ++dt)
                av[dt] = *(const short8*)(vbase + (size_t)(dt * 16 + l16) * SEQ
                                          + (k0 + pair * 32) + quad * 8);
            #pragma unroll
            for (int dt = 0; dt < 4; ++dt) {
                const short4v alo = __builtin_shufflevector(av[dt], av[dt], 0, 1, 2, 3);
                const short4v ahi = __builtin_shufflevector(av[dt], av[dt], 4, 5, 6, 7);
                #pragma unroll
                for (int qs = 0; qs < 2; ++qs) {
                    o[qs][dt] = MFMA16(alo, pb[qs][2 * pair],     o[qs][dt]);
                    o[qs][dt] = MFMA16(ahi, pb[qs][2 * pair + 1], o[qs][dt]);
                }
            }
        }
    }

    // ---- finalize per-row l (cross-quad) once
    #pragma unroll
    for (int qs = 0; qs < 2; ++qs) {
        float l = l_i[qs];
        l += __shfl_xor(l, 16, 64);
        l += __shfl_xor(l, 32, 64);
        l_i[qs] = l;
    }

    // ---- 4-way cross-wave flash merge (waves 1-3 -> LDS, wave 0 combines)
    if (wave != 0) {
        #pragma unroll
        for (int qs = 0; qs < 2; ++qs) {
            #pragma unroll
            for (int dt = 0; dt < 4; ++dt)
                #pragma unroll
                for (int r = 0; r < 4; ++r)
                    lds_o[wave - 1][qs][lane][dt * 4 + r] = o[qs][dt][r];
            if (quad == 0) {
                lds_m[wave - 1][qs][l16] = m_i[qs];
                lds_l[wave - 1][qs][l16] = l_i[qs];
            }
        }
    }
    __syncthreads();
    if (wave == 0) {
        #pragma unroll
        for (int qs = 0; qs < 2; ++qs) {
            float M = m_i[qs];
            float mp[3], lp[3];
            #pragma unroll
            for (int p = 0; p < 3; ++p) {
                mp[p] = lds_m[p][qs][l16];
                lp[p] = lds_l[p][qs][l16];
                M = fmaxf(M, mp[p]);
            }
            const float a0 = __builtin_amdgcn_exp2f(m_i[qs] - M);
            float L = l_i[qs] * a0;
            float ap[3];
            #pragma unroll
            for (int p = 0; p < 3; ++p) {
                ap[p] = __builtin_amdgcn_exp2f(mp[p] - M);
                L += lp[p] * ap[p];
            }
            const float linv = 1.0f / L;
            float* orow = og + ((size_t)(bh * SEQ + q0 + qs * 16 + l16)) * DH;
            #pragma unroll
            for (int dt = 0; dt < 4; ++dt) {
                f32x4 st;
                #pragma unroll
                for (int r = 0; r < 4; ++r) st[r] = o[qs][dt][r] * a0;
                #pragma unroll
                for (int p = 0; p < 3; ++p)
                    #pragma unroll
                    for (int r = 0; r < 4; ++r)
                        st[r] += lds_o[p][qs][lane][dt * 4 + r] * ap[p];
                #pragma unroll
                for (int r = 0; r < 4; ++r) st[r] *= linv;
                *(f32x4*)(orow + dt * 16 + quad * 4) = st;
            }
        }
    }
}

extern "C" void kernel_launch(void* const* d_in, const int* in_sizes, int n_in,
                              void* d_out, int out_size, void* d_ws, size_t ws_size,
                              hipStream_t stream)
{
    const float* q = (const float*)d_in[0];
    const float* k = (const float*)d_in[1];
    const float* v = (const float*)d_in[2];
    float* o = (float*)d_out;

    const size_t nelem = (size_t)NBH * SEQ * DH;
    short* qb  = (short*)d_ws;
    short* kbp = qb + nelem;
    short* vtp = kbp + nelem;   // 18.9 MB total

    cvt_all<<<dim3(NBH, SEQ / 64), 256, 0, stream>>>(q, k, v, qb, kbp, vtp);
    attn_fwd<<<dim3(NBH * (SEQ / 32)), 256, 0, stream>>>(qb, kbp, vtp, o);
}

// Round 3
// 189.367 us; speedup vs baseline: 1.1287x; 1.1287x over previous
//
#include <hip/hip_runtime.h>
#include <math.h>

#define SEQ   2048
#define DH    64
#define NBH   24
// scale * log2(e): softmax in exp2 domain
#define QSCALE 0.18033688011112042f

typedef __attribute__((ext_vector_type(8))) short short8;
typedef __attribute__((ext_vector_type(4))) short short4v;
typedef __attribute__((ext_vector_type(4))) float f32x4;

#define MFMA32(a, b, c) __builtin_amdgcn_mfma_f32_16x16x32_bf16((a), (b), (c), 0, 0, 0)
// gfx950 v_mfma_f32_16x16x16_bf16 (short4 operands) = the _1k builtin name.
#define MFMA16(a, b, c) __builtin_amdgcn_mfma_f32_16x16x16bf16_1k((a), (b), (c), 0, 0, 0)

// hardware RNE f32x2 -> packed bf16x2
__device__ __forceinline__ int cvtpk(float lo, float hi) {
    int r;
    asm("v_cvt_pk_bf16_f32 %0, %1, %2" : "=v"(r) : "v"(lo), "v"(hi));
    return r;
}

// ---- fused pre-pass, 32-row tiles (R2's 64-row version was latency-bound at
// 3 blocks/CU, ~60us for 55MB moved). 1536 blocks -> 6 blocks/CU; V rides the
// same coalesced float4 stream as Q/K; LDS pad 68 makes both transpose sides
// 2-way-free; one 16B vt store per thread, 4 lanes = 64B contiguous.
// vt layout (per 32-seq block): k = m*16 + qq*4 + r stored at qq*8 + m*4 + r.
__global__ __launch_bounds__(256)
void cvt_all(const float* __restrict__ q, const float* __restrict__ k,
             const float* __restrict__ v,
             short* __restrict__ qb, short* __restrict__ kb,
             short* __restrict__ vt)
{
    __shared__ float tile[32][68];
    const int t  = threadIdx.x;
    const int bh = blockIdx.x;
    const int s0 = blockIdx.y * 32;
    const size_t base = ((size_t)bh * SEQ + s0) * DH;   // 32*64 f32 = 512 float4

    #pragma unroll
    for (int i = 0; i < 2; ++i) {
        const int idx = i * 256 + t;
        float4 a = ((const float4*)(q + base))[idx];
        ((int2*)(qb + base))[idx] = make_int2(
            cvtpk(a.x * QSCALE, a.y * QSCALE),
            cvtpk(a.z * QSCALE, a.w * QSCALE));
        float4 b = ((const float4*)(k + base))[idx];
        ((int2*)(kb + base))[idx] = make_int2(cvtpk(b.x, b.y), cvtpk(b.z, b.w));
        float4 c = ((const float4*)(v + base))[idx];
        const int sl = idx >> 4, cg = (idx & 15) * 4;
        *(float4*)(&tile[sl][cg]) = c;
    }
    __syncthreads();
    {
        const int dl = t >> 2;     // d index 0..63
        const int qq = t & 3;      // quarter within the 32-seq block
        float f[8];
        #pragma unroll
        for (int r = 0; r < 4; ++r) {
            f[r]     = tile[qq * 4 + r][dl];        // m=0 half
            f[4 + r] = tile[16 + qq * 4 + r][dl];   // m=1 half
        }
        short8 pc;
        ((int*)&pc)[0] = cvtpk(f[0], f[1]);
        ((int*)&pc)[1] = cvtpk(f[2], f[3]);
        ((int*)&pc)[2] = cvtpk(f[4], f[5]);
        ((int*)&pc)[3] = cvtpk(f[6], f[7]);
        *(short8*)(vt + (size_t)bh * DH * SEQ + (size_t)dl * SEQ + s0 + qq * 8) = pc;
    }
}

// ---- main: 4-way split-K flash, shuffle-free PV (16x16x16 B-frag layout ==
// QK^T D-layout). R2 spilled ~275B/thread (WRITE_SIZE 120MB, VGPR squeezed to
// 64): demand ~150 vs the (256,4) cap of 128. Fix: fuse softmax per q-subtile
// so only ONE c[4] (16 VGPR) is live at a time. Peak liveness now
// o32+bq16+ka32+c16+pb16+misc ~ 120 < 128 -> 4 blocks/CU = 16 waves/CU.
__global__ __launch_bounds__(256, 4)
void attn_fwd(const short* __restrict__ qb, const short* __restrict__ kb,
              const short* __restrict__ vt, float* __restrict__ og)
{
    __shared__ float lds_o[3][2][64][16];
    __shared__ float lds_m[3][2][16];
    __shared__ float lds_l[3][2][16];

    const int lane = threadIdx.x & 63;
    const int wave = threadIdx.x >> 6;     // k-quarter 0..3
    const int quad = lane >> 4;
    const int l16  = lane & 15;

    // bijective XCD swizzle (1536 = 8 XCD x 192): 3 bh per XCD -> K/V L2-resident
    const int swz = (blockIdx.x & 7) * 192 + (blockIdx.x >> 3);
    const int bh  = swz >> 6;
    const int q0  = (swz & 63) * 32;

    const short* kbase = kb + (size_t)bh * SEQ * DH;
    const short* vbase = vt + (size_t)bh * DH * SEQ;

    short8 bq[2][2];
    #pragma unroll
    for (int qs = 0; qs < 2; ++qs) {
        const short* qrow = qb + ((size_t)(bh * SEQ + q0 + qs * 16 + l16)) * DH + quad * 8;
        bq[qs][0] = *(const short8*)(qrow);
        bq[qs][1] = *(const short8*)(qrow + 32);
    }

    f32x4 o[2][4];
    float m_i[2], l_i[2];
    #pragma unroll
    for (int qs = 0; qs < 2; ++qs) {
        m_i[qs] = -INFINITY; l_i[qs] = 0.f;
        #pragma unroll
        for (int dt = 0; dt < 4; ++dt) o[qs][dt] = (f32x4){0.f, 0.f, 0.f, 0.f};
    }

    const size_t klane = (size_t)l16 * DH + quad * 8;

    int k0 = wave * (SEQ / 4);
    short8 ka[8];
    #pragma unroll
    for (int mt = 0; mt < 4; ++mt) {
        const short* krow = kbase + (size_t)(k0 + mt * 16) * DH + klane;
        ka[2 * mt]     = *(const short8*)(krow);
        ka[2 * mt + 1] = *(const short8*)(krow + 32);
    }

    #pragma unroll 1
    for (int iter = 0; iter < 8; ++iter, k0 += 64) {
        short4v pb[2][4];

        // ---- per q-subtile: S^T = K @ Q^T then softmax (c[4] liveness only)
        #pragma unroll
        for (int qs = 0; qs < 2; ++qs) {
            f32x4 c[4];
            #pragma unroll
            for (int mt = 0; mt < 4; ++mt) {
                f32x4 z = (f32x4){0.f, 0.f, 0.f, 0.f};
                z = MFMA32(ka[2 * mt],     bq[qs][0], z);
                z = MFMA32(ka[2 * mt + 1], bq[qs][1], z);
                c[mt] = z;
            }

            float tm[4];
            #pragma unroll
            for (int e = 0; e < 4; ++e)
                tm[e] = fmaxf(fmaxf(c[0][e], c[1][e]), fmaxf(c[2][e], c[3][e]));
            const float lmax = fmaxf(fmaxf(tm[0], tm[1]), fmaxf(tm[2], tm[3]));
            // defer-max: only rescale when some row grew past m+8 (rare)
            if (!__all(lmax <= m_i[qs] + 8.f)) {
                float vmax = fmaxf(lmax, __shfl_xor(lmax, 16, 64));
                vmax = fmaxf(vmax, __shfl_xor(vmax, 32, 64));
                vmax = fmaxf(vmax, m_i[qs]);
                const float alpha = __builtin_amdgcn_exp2f(m_i[qs] - vmax);
                m_i[qs] = vmax;
                l_i[qs] *= alpha;
                #pragma unroll
                for (int dt = 0; dt < 4; ++dt)
                    #pragma unroll
                    for (int r = 0; r < 4; ++r) o[qs][dt][r] *= alpha;
            }
            const float m = m_i[qs];
            float rs = 0.f;
            #pragma unroll
            for (int mt = 0; mt < 4; ++mt) {
                float p[4];
                #pragma unroll
                for (int r = 0; r < 4; ++r) {
                    p[r] = __builtin_amdgcn_exp2f(c[mt][r] - m);
                    rs += p[r];
                }
                int2 w = make_int2(cvtpk(p[0], p[1]), cvtpk(p[2], p[3]));
                pb[qs][mt] = __builtin_bit_cast(short4v, w);
            }
            l_i[qs] += rs;       // per-lane partial; cross-quad reduce at end
        }

        // ---- prefetch next chunk's K frags (in flight through PV)
        if (iter < 7) {
            const int k0n = k0 + 64;
            #pragma unroll
            for (int mt = 0; mt < 4; ++mt) {
                const short* krow = kbase + (size_t)(k0n + mt * 16) * DH + klane;
                ka[2 * mt]     = *(const short8*)(krow);
                ka[2 * mt + 1] = *(const short8*)(krow + 32);
            }
        }

        // ---- PV: shuffle-free. One 16B load = A-frags for both 16-blocks
        // of a 32-chunk (k-permuted vt layout).
        #pragma unroll
        for (int pair = 0; pair < 2; ++pair) {
            short8 av[4];
            #pragma unroll
            for (int dt = 0; dt < 4; ++dt)
                av[dt] = *(const short8*)(vbase + (size_t)(dt * 16 + l16) * SEQ
                                          + (k0 + pair * 32) + quad * 8);
            #pragma unroll
            for (int dt = 0; dt < 4; ++dt) {
                const short4v alo = __builtin_shufflevector(av[dt], av[dt], 0, 1, 2, 3);
                const short4v ahi = __builtin_shufflevector(av[dt], av[dt], 4, 5, 6, 7);
                #pragma unroll
                for (int qs = 0; qs < 2; ++qs) {
                    o[qs][dt] = MFMA16(alo, pb[qs][2 * pair],     o[qs][dt]);
                    o[qs][dt] = MFMA16(ahi, pb[qs][2 * pair + 1], o[qs][dt]);
                }
            }
        }
    }

    // ---- finalize per-row l (cross-quad) once
    #pragma unroll
    for (int qs = 0; qs < 2; ++qs) {
        float l = l_i[qs];
        l += __shfl_xor(l, 16, 64);
        l += __shfl_xor(l, 32, 64);
        l_i[qs] = l;
    }

    // ---- 4-way cross-wave flash merge (waves 1-3 -> LDS, wave 0 combines)
    if (wave != 0) {
        #pragma unroll
        for (int qs = 0; qs < 2; ++qs) {
            #pragma unroll
            for (int dt = 0; dt < 4; ++dt)
                #pragma unroll
                for (int r = 0; r < 4; ++r)
                    lds_o[wave - 1][qs][lane][dt * 4 + r] = o[qs][dt][r];
            if (quad == 0) {
                lds_m[wave - 1][qs][l16] = m_i[qs];
                lds_l[wave - 1][qs][l16] = l_i[qs];
            }
        }
    }
    __syncthreads();
    if (wave == 0) {
        #pragma unroll
        for (int qs = 0; qs < 2; ++qs) {
            float M = m_i[qs];
            float mp[3], lp[3];
            #pragma unroll
            for (int p = 0; p < 3; ++p) {
                mp[p] = lds_m[p][qs][l16];
                lp[p] = lds_l[p][qs][l16];
                M = fmaxf(M, mp[p]);
            }
            const float a0 = __builtin_amdgcn_exp2f(m_i[qs] - M);
            float L = l_i[qs] * a0;
            float ap[3];
            #pragma unroll
            for (int p = 0; p < 3; ++p) {
                ap[p] = __builtin_amdgcn_exp2f(mp[p] - M);
                L += lp[p] * ap[p];
            }
            const float linv = 1.0f / L;
            float* orow = og + ((size_t)(bh * SEQ + q0 + qs * 16 + l16)) * DH;
            #pragma unroll
            for (int dt = 0; dt < 4; ++dt) {
                f32x4 st;
                #pragma unroll
                for (int r = 0; r < 4; ++r) st[r] = o[qs][dt][r] * a0;
                #pragma unroll
                for (int p = 0; p < 3; ++p)
                    #pragma unroll
                    for (int r = 0; r < 4; ++r)
                        st[r] += lds_o[p][qs][lane][dt * 4 + r] * ap[p];
                #pragma unroll
                for (int r = 0; r < 4; ++r) st[r] *= linv;
                *(f32x4*)(orow + dt * 16 + quad * 4) = st;
            }
        }
    }
}

extern "C" void kernel_launch(void* const* d_in, const int* in_sizes, int n_in,
                              void* d_out, int out_size, void* d_ws, size_t ws_size,
                              hipStream_t stream)
{
    const float* q = (const float*)d_in[0];
    const float* k = (const float*)d_in[1];
    const float* v = (const float*)d_in[2];
    float* o = (float*)d_out;

    const size_t nelem = (size_t)NBH * SEQ * DH;
    short* qb  = (short*)d_ws;
    short* kbp = qb + nelem;
    short* vtp = kbp + nelem;   // 18.9 MB total

    cvt_all<<<dim3(NBH, SEQ / 32), 256, 0, stream>>>(q, k, v, qb, kbp, vtp);
    attn_fwd<<<dim3(NBH * (SEQ / 32)), 256, 0, stream>>>(qb, kbp, vtp, o);
}

// Round 4
// 174.405 us; speedup vs baseline: 1.2255x; 1.0858x over previous
//
#include <hip/hip_runtime.h>
#include <math.h>

#define SEQ   2048
#define DH    64
#define NBH   24
// scale * log2(e): softmax in exp2 domain
#define QSCALE 0.18033688011112042f

typedef __attribute__((ext_vector_type(8))) short short8;
typedef __attribute__((ext_vector_type(4))) short short4v;
typedef __attribute__((ext_vector_type(4))) float f32x4;

#define MFMA32(a, b, c) __builtin_amdgcn_mfma_f32_16x16x32_bf16((a), (b), (c), 0, 0, 0)
// gfx950 v_mfma_f32_16x16x16_bf16 (short4 operands) = the _1k builtin name.
#define MFMA16(a, b, c) __builtin_amdgcn_mfma_f32_16x16x16bf16_1k((a), (b), (c), 0, 0, 0)

// hardware RNE f32x2 -> packed bf16x2
__device__ __forceinline__ int cvtpk(float lo, float hi) {
    int r;
    asm("v_cvt_pk_bf16_f32 %0, %1, %2" : "=v"(r) : "v"(lo), "v"(hi));
    return r;
}

// ---- fused pre-pass, 32-row tiles. 1536 blocks -> 6 blocks/CU; V rides the
// same coalesced float4 stream as Q/K; one 16B vt store per thread.
// vt layout (per 32-seq block): k = m*16 + qq*4 + r stored at qq*8 + m*4 + r.
// (R2->R3 showed the non-attn time gap is harness overhead, not this kernel —
// leaving it alone.)
__global__ __launch_bounds__(256)
void cvt_all(const float* __restrict__ q, const float* __restrict__ k,
             const float* __restrict__ v,
             short* __restrict__ qb, short* __restrict__ kb,
             short* __restrict__ vt)
{
    __shared__ float tile[32][68];
    const int t  = threadIdx.x;
    const int bh = blockIdx.x;
    const int s0 = blockIdx.y * 32;
    const size_t base = ((size_t)bh * SEQ + s0) * DH;   // 32*64 f32 = 512 float4

    #pragma unroll
    for (int i = 0; i < 2; ++i) {
        const int idx = i * 256 + t;
        float4 a = ((const float4*)(q + base))[idx];
        ((int2*)(qb + base))[idx] = make_int2(
            cvtpk(a.x * QSCALE, a.y * QSCALE),
            cvtpk(a.z * QSCALE, a.w * QSCALE));
        float4 b = ((const float4*)(k + base))[idx];
        ((int2*)(kb + base))[idx] = make_int2(cvtpk(b.x, b.y), cvtpk(b.z, b.w));
        float4 c = ((const float4*)(v + base))[idx];
        const int sl = idx >> 4, cg = (idx & 15) * 4;
        *(float4*)(&tile[sl][cg]) = c;
    }
    __syncthreads();
    {
        const int dl = t >> 2;     // d index 0..63
        const int qq = t & 3;      // quarter within the 32-seq block
        float f[8];
        #pragma unroll
        for (int r = 0; r < 4; ++r) {
            f[r]     = tile[qq * 4 + r][dl];        // m=0 half
            f[4 + r] = tile[16 + qq * 4 + r][dl];   // m=1 half
        }
        short8 pc;
        ((int*)&pc)[0] = cvtpk(f[0], f[1]);
        ((int*)&pc)[1] = cvtpk(f[2], f[3]);
        ((int*)&pc)[2] = cvtpk(f[4], f[5]);
        ((int*)&pc)[3] = cvtpk(f[6], f[7]);
        *(short8*)(vt + (size_t)bh * DH * SEQ + (size_t)dl * SEQ + s0 + qq * 8) = pc;
    }
}

// ---- main: 4-way split-K flash, shuffle-free PV (16x16x16 B-frag layout ==
// QK^T D-layout). R3 post-mortem: (256,4) cap=128 unified regs vs ~150 demand
// -> 19MB/dispatch scratch traffic (WRITE 31.5MB vs 12.6 ideal), and measured
// occupancy was only ~11.5 waves/CU anyway. (256,3) caps ~170: zero spill at
// the SAME residency. Spill-free > extra-occupancy here (the extra occupancy
// never materialized).
__global__ __launch_bounds__(256, 3)
void attn_fwd(const short* __restrict__ qb, const short* __restrict__ kb,
              const short* __restrict__ vt, float* __restrict__ og)
{
    __shared__ float lds_o[3][2][64][16];
    __shared__ float lds_m[3][2][16];
    __shared__ float lds_l[3][2][16];

    const int lane = threadIdx.x & 63;
    const int wave = threadIdx.x >> 6;     // k-quarter 0..3
    const int quad = lane >> 4;
    const int l16  = lane & 15;

    // bijective XCD swizzle (1536 = 8 XCD x 192): 3 bh per XCD -> K/V L2-resident
    const int swz = (blockIdx.x & 7) * 192 + (blockIdx.x >> 3);
    const int bh  = swz >> 6;
    const int q0  = (swz & 63) * 32;

    const short* kbase = kb + (size_t)bh * SEQ * DH;
    const short* vbase = vt + (size_t)bh * DH * SEQ;

    short8 bq[2][2];
    #pragma unroll
    for (int qs = 0; qs < 2; ++qs) {
        const short* qrow = qb + ((size_t)(bh * SEQ + q0 + qs * 16 + l16)) * DH + quad * 8;
        bq[qs][0] = *(const short8*)(qrow);
        bq[qs][1] = *(const short8*)(qrow + 32);
    }

    f32x4 o[2][4];
    float m_i[2], l_i[2];
    #pragma unroll
    for (int qs = 0; qs < 2; ++qs) {
        m_i[qs] = -INFINITY; l_i[qs] = 0.f;
        #pragma unroll
        for (int dt = 0; dt < 4; ++dt) o[qs][dt] = (f32x4){0.f, 0.f, 0.f, 0.f};
    }

    const size_t klane = (size_t)l16 * DH + quad * 8;

    int k0 = wave * (SEQ / 4);
    short8 ka[8];
    #pragma unroll
    for (int mt = 0; mt < 4; ++mt) {
        const short* krow = kbase + (size_t)(k0 + mt * 16) * DH + klane;
        ka[2 * mt]     = *(const short8*)(krow);
        ka[2 * mt + 1] = *(const short8*)(krow + 32);
    }

    #pragma unroll 1
    for (int iter = 0; iter < 8; ++iter, k0 += 64) {
        short4v pb[2][4];

        // ---- per q-subtile: S^T = K @ Q^T then softmax (c[4] liveness only)
        #pragma unroll
        for (int qs = 0; qs < 2; ++qs) {
            f32x4 c[4];
            #pragma unroll
            for (int mt = 0; mt < 4; ++mt) {
                f32x4 z = (f32x4){0.f, 0.f, 0.f, 0.f};
                z = MFMA32(ka[2 * mt],     bq[qs][0], z);
                z = MFMA32(ka[2 * mt + 1], bq[qs][1], z);
                c[mt] = z;
            }

            float tm[4];
            #pragma unroll
            for (int e = 0; e < 4; ++e)
                tm[e] = fmaxf(fmaxf(c[0][e], c[1][e]), fmaxf(c[2][e], c[3][e]));
            const float lmax = fmaxf(fmaxf(tm[0], tm[1]), fmaxf(tm[2], tm[3]));
            // defer-max: only rescale when some row grew past m+8 (rare)
            if (!__all(lmax <= m_i[qs] + 8.f)) {
                float vmax = fmaxf(lmax, __shfl_xor(lmax, 16, 64));
                vmax = fmaxf(vmax, __shfl_xor(vmax, 32, 64));
                vmax = fmaxf(vmax, m_i[qs]);
                const float alpha = __builtin_amdgcn_exp2f(m_i[qs] - vmax);
                m_i[qs] = vmax;
                l_i[qs] *= alpha;
                #pragma unroll
                for (int dt = 0; dt < 4; ++dt)
                    #pragma unroll
                    for (int r = 0; r < 4; ++r) o[qs][dt][r] *= alpha;
            }
            const float m = m_i[qs];
            float rs = 0.f;
            #pragma unroll
            for (int mt = 0; mt < 4; ++mt) {
                float p[4];
                #pragma unroll
                for (int r = 0; r < 4; ++r) {
                    p[r] = __builtin_amdgcn_exp2f(c[mt][r] - m);
                    rs += p[r];
                }
                int2 w = make_int2(cvtpk(p[0], p[1]), cvtpk(p[2], p[3]));
                pb[qs][mt] = __builtin_bit_cast(short4v, w);
            }
            l_i[qs] += rs;       // per-lane partial; cross-quad reduce at end
        }

        // ---- prefetch next chunk's K frags (in flight through PV)
        if (iter < 7) {
            const int k0n = k0 + 64;
            #pragma unroll
            for (int mt = 0; mt < 4; ++mt) {
                const short* krow = kbase + (size_t)(k0n + mt * 16) * DH + klane;
                ka[2 * mt]     = *(const short8*)(krow);
                ka[2 * mt + 1] = *(const short8*)(krow + 32);
            }
        }

        // ---- PV: shuffle-free. One 16B load = A-frags for both 16-blocks
        // of a 32-chunk (k-permuted vt layout).
        #pragma unroll
        for (int pair = 0; pair < 2; ++pair) {
            short8 av[4];
            #pragma unroll
            for (int dt = 0; dt < 4; ++dt)
                av[dt] = *(const short8*)(vbase + (size_t)(dt * 16 + l16) * SEQ
                                          + (k0 + pair * 32) + quad * 8);
            #pragma unroll
            for (int dt = 0; dt < 4; ++dt) {
                const short4v alo = __builtin_shufflevector(av[dt], av[dt], 0, 1, 2, 3);
                const short4v ahi = __builtin_shufflevector(av[dt], av[dt], 4, 5, 6, 7);
                #pragma unroll
                for (int qs = 0; qs < 2; ++qs) {
                    o[qs][dt] = MFMA16(alo, pb[qs][2 * pair],     o[qs][dt]);
                    o[qs][dt] = MFMA16(ahi, pb[qs][2 * pair + 1], o[qs][dt]);
                }
            }
        }
    }

    // ---- finalize per-row l (cross-quad) once
    #pragma unroll
    for (int qs = 0; qs < 2; ++qs) {
        float l = l_i[qs];
        l += __shfl_xor(l, 16, 64);
        l += __shfl_xor(l, 32, 64);
        l_i[qs] = l;
    }

    // ---- 4-way cross-wave flash merge (waves 1-3 -> LDS, wave 0 combines)
    if (wave != 0) {
        #pragma unroll
        for (int qs = 0; qs < 2; ++qs) {
            #pragma unroll
            for (int dt = 0; dt < 4; ++dt)
                #pragma unroll
                for (int r = 0; r < 4; ++r)
                    lds_o[wave - 1][qs][lane][dt * 4 + r] = o[qs][dt][r];
            if (quad == 0) {
                lds_m[wave - 1][qs][l16] = m_i[qs];
                lds_l[wave - 1][qs][l16] = l_i[qs];
            }
        }
    }
    __syncthreads();
    if (wave == 0) {
        #pragma unroll
        for (int qs = 0; qs < 2; ++qs) {
            float M = m_i[qs];
            float mp[3], lp[3];
            #pragma unroll
            for (int p = 0; p < 3; ++p) {
                mp[p] = lds_m[p][qs][l16];
                lp[p] = lds_l[p][qs][l16];
                M = fmaxf(M, mp[p]);
            }
            const float a0 = __builtin_amdgcn_exp2f(m_i[qs] - M);
            float L = l_i[qs] * a0;
            float ap[3];
            #pragma unroll
            for (int p = 0; p < 3; ++p) {
                ap[p] = __builtin_amdgcn_exp2f(mp[p] - M);
                L += lp[p] * ap[p];
            }
            const float linv = 1.0f / L;
            float* orow = og + ((size_t)(bh * SEQ + q0 + qs * 16 + l16)) * DH;
            #pragma unroll
            for (int dt = 0; dt < 4; ++dt) {
                f32x4 st;
                #pragma unroll
                for (int r = 0; r < 4; ++r) st[r] = o[qs][dt][r] * a0;
                #pragma unroll
                for (int p = 0; p < 3; ++p)
                    #pragma unroll
                    for (int r = 0; r < 4; ++r)
                        st[r] += lds_o[p][qs][lane][dt * 4 + r] * ap[p];
                #pragma unroll
                for (int r = 0; r < 4; ++r) st[r] *= linv;
                *(f32x4*)(orow + dt * 16 + quad * 4) = st;
            }
        }
    }
}

extern "C" void kernel_launch(void* const* d_in, const int* in_sizes, int n_in,
                              void* d_out, int out_size, void* d_ws, size_t ws_size,
                              hipStream_t stream)
{
    const float* q = (const float*)d_in[0];
    const float* k = (const float*)d_in[1];
    const float* v = (const float*)d_in[2];
    float* o = (float*)d_out;

    const size_t nelem = (size_t)NBH * SEQ * DH;
    short* qb  = (short*)d_ws;
    short* kbp = qb + nelem;
    short* vtp = kbp + nelem;   // 18.9 MB total

    cvt_all<<<dim3(NBH, SEQ / 32), 256, 0, stream>>>(q, k, v, qb, kbp, vtp);
    attn_fwd<<<dim3(NBH * (SEQ / 32)), 256, 0, stream>>>(qb, kbp, vtp, o);
}